// Round 8
// baseline (9286.354 us; speedup 1.0000x reference)
//
#include <hip/hip_runtime.h>
#include <hip/hip_bf16.h>
#include <cstdint>
#include <cstddef>

// Problem constants
#define T_LEN 1024
#define B_SZ  64
#define H_DIM 512
#define D_IN  512

// Decomposition: 2 dirs x 4 batch-groups (16 rows) x 32 col-groups (16 cols).
// Each block runs BOTH layers (layer-1 trails layer-0 by 2 supersteps).
#define NBG   4
#define GROUP 32
#define BS    16
#define CW    16

typedef __attribute__((ext_vector_type(8))) short short8;
typedef __attribute__((ext_vector_type(4))) float f32x4;
typedef __attribute__((ext_vector_type(4))) int   i32x4;

// LDS layout (bytes): Whh0 48K | Whh1 48K | H0 16K | H1 16K | XY 16K | D 5K = 149K
#define OFF_WHH0 0
#define OFF_WHH1 49152
#define OFF_H0   98304
#define OFF_H1   114688
#define OFF_XY   131072
#define OFF_D    147456
#define SMEM_BYTES 152576

// Tagged-unit exchange geometry (identical to round 6).
// Unit = 16B: u16[0..6] = 7 bf16 values, u16[7] = step tag (>=1; memset gives 0).
// Per (state,row): 32 col-groups x 3 units = 1536B. Per state: 16 rows.
#define ROW_BYTES   1536
#define STATE_BYTES (16 * ROW_BYTES)   // 24576
#define HT_BYTES    (32 * STATE_BYTES) // 786432: states = (layer*2+par)*8+grp
#define YT_BYTES    (32 * STATE_BYTES) // 786432: states = slot*8+grp

__device__ __forceinline__ int swz(int row, int byteoff) {
  return byteoff ^ ((row & 7) << 4);   // break stride-1024 LDS bank conflicts
}

__device__ __forceinline__ unsigned short f2bf(float f) {
  unsigned u = __float_as_uint(f);
  return (unsigned short)((u + 0x7FFFu + ((u >> 16) & 1u)) >> 16);   // RNE
}

__device__ __forceinline__ short8 pack8(float4 a, float4 b) {
  short8 v;
  v[0] = (short)f2bf(a.x); v[1] = (short)f2bf(a.y);
  v[2] = (short)f2bf(a.z); v[3] = (short)f2bf(a.w);
  v[4] = (short)f2bf(b.x); v[5] = (short)f2bf(b.y);
  v[6] = (short)f2bf(b.z); v[7] = (short)f2bf(b.w);
  return v;
}

__device__ __forceinline__ unsigned cvtpk(float lo, float hi) {
  unsigned r;
  asm("v_cvt_pk_bf16_f32 %0, %1, %2" : "=v"(r) : "v"(lo), "v"(hi));
  return r;
}
__device__ __forceinline__ short8 cvtpk8(float4 a, float4 b) {
  union { unsigned u[4]; short8 s; } cv;
  cv.u[0] = cvtpk(a.x, a.y); cv.u[1] = cvtpk(a.z, a.w);
  cv.u[2] = cvtpk(b.x, b.y); cv.u[3] = cvtpk(b.z, b.w);
  return cv.s;
}

__device__ __forceinline__ float sigm(float x) { return 1.0f / (1.0f + __expf(-x)); }
__device__ __forceinline__ float fast_tanh(float x) { return 1.0f - 2.0f / (__expf(2.0f * x) + 1.0f); }

// agent-scope (sc1) 16B store: fire-and-forget tagged unit (round-6 proven)
__device__ __forceinline__ void st16(void* p, i32x4 d) {
  asm volatile("global_store_dwordx4 %0, %1, off sc1" :: "v"(p), "v"(d) : "memory");
}

// repack two producers' 7/7/2-packed triple into contiguous bf16x8 pairs
__device__ __forceinline__ void repack_triple(i32x4 Ua, i32x4 Ub, i32x4 Uc,
                                              short8& s0, short8& s1) {
  union { unsigned u[4]; short8 s; } A, B;
  A.u[0] = (unsigned)Ua[0];
  A.u[1] = (unsigned)Ua[1];
  A.u[2] = (unsigned)Ua[2];
  A.u[3] = ((unsigned)Ua[3] & 0xffffu) | ((unsigned)Ub[0] << 16);
  B.u[0] = ((unsigned)Ub[0] >> 16) | ((unsigned)Ub[1] << 16);
  B.u[1] = ((unsigned)Ub[1] >> 16) | ((unsigned)Ub[2] << 16);
  B.u[2] = ((unsigned)Ub[2] >> 16) | (((unsigned)Ub[3] & 0xffffu) << 16);
  B.u[3] = (unsigned)Uc[0];
  s0 = A.s; s1 = B.s;
}

__global__ __launch_bounds__(256, 1)
void gru_fused(const float* __restrict__ x,
               const float* __restrict__ enc,
               const float* __restrict__ WihF, const float* __restrict__ WhhF,
               const float* __restrict__ bihF, const float* __restrict__ bhhF,
               const float* __restrict__ WihB, const float* __restrict__ WhhB,
               const float* __restrict__ bihB, const float* __restrict__ bhhB,
               float* __restrict__ dout,
               char* __restrict__ hT,
               char* __restrict__ yT)
{
  __shared__ alignas(16) char smem[SMEM_BYTES];

  const int bid  = blockIdx.x;
  const int grp  = bid & 7;          // dir*4+bg
  const int dir  = grp >> 2;
  const int bg   = grp & 3;
  const int cg   = bid >> 3;         // col-group 0..31
  const int tid  = threadIdx.x;
  const int wv   = tid >> 6;
  const int tb   = tid >> 4;         // batch-local row / staging row
  const int tc   = tid & 15;         // col-local / staging segment
  const int lrow = tc;               // MFMA fragment row
  const int q    = tb & 3;           // MFMA k-quarter
  const int hc0  = cg * CW;
  const int hcol = hc0 + tc;
  const int bglobal = bg * BS + tb;
  const int dircol  = dir * H_DIM;

  const bool isPub = (tc == 0) | (tc == 7) | (tc == 14);
  const int  which = (tc == 0) ? 0 : ((tc == 7) ? 1 : 2);

  const float* Wih0 = (dir ? WihB : WihF);
  const float* Whh0 = (dir ? WhhB : WhhF);
  const float* bih0 = (dir ? bihB : bihF);
  const float* bhh0 = (dir ? bhhB : bhhF);
  const float* Wih1 = Wih0 + (size_t)3 * H_DIM * D_IN;
  const float* Whh1 = Whh0 + (size_t)3 * H_DIM * H_DIM;
  const float* bih1 = bih0 + 3 * H_DIM;
  const float* bhh1 = bhh0 + 3 * H_DIM;

  // ---- Stage Whh for BOTH layers into LDS (once) ----
  #pragma unroll
  for (int g = 0; g < 3; ++g) {
    {
      const float* s = Whh0 + (size_t)(g * H_DIM + hc0 + tb) * H_DIM + tc * 32;
      char* r = smem + OFF_WHH0 + g * 16384 + tb * 1024;
      #pragma unroll
      for (int u = 0; u < 4; ++u) {
        float4 a = ((const float4*)s)[u * 2];
        float4 b = ((const float4*)s)[u * 2 + 1];
        *(short8*)(r + swz(tb, tc * 64 + u * 16)) = pack8(a, b);
      }
    }
    {
      const float* s = Whh1 + (size_t)(g * H_DIM + hc0 + tb) * H_DIM + tc * 32;
      char* r = smem + OFF_WHH1 + g * 16384 + tb * 1024;
      #pragma unroll
      for (int u = 0; u < 4; ++u) {
        float4 a = ((const float4*)s)[u * 2];
        float4 b = ((const float4*)s)[u * 2 + 1];
        *(short8*)(r + swz(tb, tc * 64 + u * 16)) = pack8(a, b);
      }
    }
  }

  // ---- Persistent Wih B-fragments in registers, both layers ----
  short8 wf0[16], wf1[16];
  if (wv < 3) {
    const float* p0 = Wih0 + (size_t)(wv * H_DIM + hc0 + lrow) * D_IN;
    const float* p1 = Wih1 + (size_t)(wv * H_DIM + hc0 + lrow) * D_IN;
    #pragma unroll
    for (int kc = 0; kc < 16; ++kc) {
      const int k0 = kc * 32 + q * 8;
      wf0[kc] = cvtpk8(*(const float4*)(p0 + k0), *(const float4*)(p0 + k0 + 4));
      wf1[kc] = cvtpk8(*(const float4*)(p1 + k0), *(const float4*)(p1 + k0 + 4));
    }
  }

  // ---- Biases and initial hidden states ----
  const float b_r0  = bih0[hcol] + bhh0[hcol];
  const float b_z0  = bih0[H_DIM + hcol] + bhh0[H_DIM + hcol];
  const float b_xn0 = bih0[2 * H_DIM + hcol];
  const float b_hn0 = bhh0[2 * H_DIM + hcol];
  const float b_r1  = bih1[hcol] + bhh1[hcol];
  const float b_z1  = bih1[H_DIM + hcol] + bhh1[H_DIM + hcol];
  const float b_xn1 = bih1[2 * H_DIM + hcol];
  const float b_hn1 = bhh1[2 * H_DIM + hcol];
  float h0reg = enc[(size_t)bglobal * 2 * H_DIM + dircol + hcol];
  float h1reg = enc[(size_t)B_SZ * 2 * H_DIM + (size_t)bglobal * 2 * H_DIM + dircol + hcol];

  // ---- exchange-buffer base helpers ----
  auto stateH = [&](int layer, int par) -> char* {
    return hT + (size_t)(((layer * 2 + par) * 8) + grp) * STATE_BYTES;
  };
  auto stateY = [&](int slot) -> char* {
    return yT + (size_t)(slot * 8 + grp) * STATE_BYTES;
  };

  auto pubH = [&](float val, char* sb, unsigned tag) {
    unsigned v  = f2bf(val);
    unsigned v1 = __shfl_down(v, 1), v2 = __shfl_down(v, 2), v3 = __shfl_down(v, 3);
    unsigned v4 = __shfl_down(v, 4), v5 = __shfl_down(v, 5), v6 = __shfl_down(v, 6);
    if (isPub) {
      i32x4 U;
      U[0] = (int)(v  | (v1 << 16));
      U[1] = (int)(v2 | (v3 << 16));
      U[2] = (int)(v4 | (v5 << 16));
      U[3] = (int)((v6 & 0xffffu) | (tag << 16));
      st16(sb + (size_t)tb * ROW_BYTES + cg * 48 + which * 16, U);
    }
  };
  auto pubDual = [&](float val, char* sbH, unsigned tagH, char* sbY, unsigned tagY) {
    unsigned v  = f2bf(val);
    unsigned v1 = __shfl_down(v, 1), v2 = __shfl_down(v, 2), v3 = __shfl_down(v, 3);
    unsigned v4 = __shfl_down(v, 4), v5 = __shfl_down(v, 5), v6 = __shfl_down(v, 6);
    if (isPub) {
      i32x4 U;
      U[0] = (int)(v  | (v1 << 16));
      U[1] = (int)(v2 | (v3 << 16));
      U[2] = (int)(v4 | (v5 << 16));
      i32x4 Uh = U, Uy = U;
      Uh[3] = (int)((v6 & 0xffffu) | (tagH << 16));
      Uy[3] = (int)((v6 & 0xffffu) | (tagY << 16));
      const size_t off = (size_t)tb * ROW_BYTES + cg * 48 + which * 16;
      st16(sbH + off, Uh);
      st16(sbY + off, Uy);
    }
  };

  // ---- burst gather pieces: issue 6 loads (no wait), check 6 tags, repack ----
  auto issue6 = [&](const char* sb, i32x4* U) {
    const char* a0 = sb + (size_t)tb * ROW_BYTES + (2 * tc) * 48;
    const char* a1 = a0 + 48;
    asm volatile(
      "global_load_dwordx4 %0, %6, off sc1\n\t"
      "global_load_dwordx4 %1, %6, off offset:16 sc1\n\t"
      "global_load_dwordx4 %2, %6, off offset:32 sc1\n\t"
      "global_load_dwordx4 %3, %7, off sc1\n\t"
      "global_load_dwordx4 %4, %7, off offset:16 sc1\n\t"
      "global_load_dwordx4 %5, %7, off offset:32 sc1"
      : "=&v"(U[0]), "=&v"(U[1]), "=&v"(U[2]), "=&v"(U[3]), "=&v"(U[4]), "=&v"(U[5])
      : "v"(a0), "v"(a1)
      : "memory");
  };
  auto check6 = [&](const i32x4* U, unsigned tag) -> bool {
    return (((unsigned)U[0][3] >> 16) == tag) & (((unsigned)U[1][3] >> 16) == tag) &
           (((unsigned)U[2][3] >> 16) == tag) & (((unsigned)U[3][3] >> 16) == tag) &
           (((unsigned)U[4][3] >> 16) == tag) & (((unsigned)U[5][3] >> 16) == tag);
  };
  auto retry6 = [&](const char* sb, unsigned tag, i32x4* U) {
    for (;;) {
      __builtin_amdgcn_s_sleep(1);
      issue6(sb, U);
      asm volatile("s_waitcnt vmcnt(0)" ::: "memory");
      __builtin_amdgcn_sched_barrier(0);
      if (check6(U, tag)) break;
    }
  };
  auto repack6 = [&](const i32x4* U, int ldsOff) {
    short8 s0, s1, s2, s3;
    repack_triple(U[0], U[1], U[2], s0, s1);
    repack_triple(U[3], U[4], U[5], s2, s3);
    char* lh = smem + ldsOff + tb * 1024;
    *(short8*)(lh + swz(tb, tc * 64 +  0)) = s0;
    *(short8*)(lh + swz(tb, tc * 64 + 16)) = s1;
    *(short8*)(lh + swz(tb, tc * 64 + 32)) = s2;
    *(short8*)(lh + swz(tb, tc * 64 + 48)) = s3;
  };

  auto stage_x = [&](int pos, int ldsOff) {   // fp32 global row -> bf16 LDS tile
    const float* xrow = x + ((size_t)bglobal * T_LEN + pos) * D_IN;
    const float4* s4 = (const float4*)(xrow + tc * 32);
    char* lx = smem + ldsOff + tb * 1024;
    #pragma unroll
    for (int u = 0; u < 4; ++u) {
      float4 a = s4[u * 2];
      float4 b = s4[u * 2 + 1];
      *(short8*)(lx + swz(tb, tc * 64 + u * 16)) = pack8(a, b);
    }
  };
  auto xpart = [&](const short8* wf, int aOff, f32x4& am) {   // A(LDS) x Wih(regs)
    if (wv < 3) {
      char* xr = smem + aOff + lrow * 1024;
      #pragma unroll
      for (int kc = 0; kc < 16; ++kc) {
        short8 a = *(const short8*)(xr + swz(lrow, kc * 64 + q * 16));
        am = __builtin_amdgcn_mfma_f32_16x16x32_bf16(a, wf[kc], am, 0, 0, 0);
      }
    }
  };
  auto hpart = [&](int whhOff, int hOff, f32x4& am, f32x4& ah) {  // H(LDS) x Whh(LDS)
    char* hr = smem + hOff + lrow * 1024;
    if (wv < 2) {
      char* wrow = smem + whhOff + wv * 16384 + lrow * 1024;
      #pragma unroll
      for (int kc = 0; kc < 16; ++kc) {
        short8 a = *(const short8*)(hr + swz(lrow, kc * 64 + q * 16));
        short8 b = *(const short8*)(wrow + swz(lrow, kc * 64 + q * 16));
        am = __builtin_amdgcn_mfma_f32_16x16x32_bf16(a, b, am, 0, 0, 0);
      }
    } else {
      char* wrow = smem + whhOff + 2 * 16384 + lrow * 1024;
      const int k0 = (wv == 2) ? 0 : 8;
      #pragma unroll
      for (int kc = 0; kc < 8; ++kc) {
        short8 a = *(const short8*)(hr + swz(lrow, (k0 + kc) * 64 + q * 16));
        short8 b = *(const short8*)(wrow + swz(lrow, (k0 + kc) * 64 + q * 16));
        ah = __builtin_amdgcn_mfma_f32_16x16x32_bf16(a, b, ah, 0, 0, 0);
      }
    }
  };
  auto dwrite = [&](const f32x4& am, const f32x4& ah) {
    if (wv < 3) {
      float* dt = (float*)(smem + OFF_D + wv * 1024);
      #pragma unroll
      for (int r = 0; r < 4; ++r)
        dt[(q * 4 + r) * 16 + ((lrow + 4 * q) & 15)] = am[r];
    }
    if (wv >= 2) {
      float* dt = (float*)(smem + OFF_D + (wv + 1) * 1024);
      #pragma unroll
      for (int r = 0; r < 4; ++r)
        dt[(q * 4 + r) * 16 + ((lrow + 4 * q) & 15)] = ah[r];
    }
  };
  auto gates = [&](float br, float bz, float bxn, float bhn, float hprev) -> float {
    const float* Dr  = (const float*)(smem + OFF_D);
    const float* Dz  = (const float*)(smem + OFF_D + 1024);
    const float* Dxn = (const float*)(smem + OFF_D + 2048);
    const float* Dha = (const float*)(smem + OFF_D + 3072);
    const float* Dhb = (const float*)(smem + OFF_D + 4096);
    const int e = tb * 16 + ((tc + 4 * (tb >> 2)) & 15);
    const float r = sigm(Dr[e] + br);
    const float z = sigm(Dz[e] + bz);
    const float n = fast_tanh(Dxn[e] + bxn + r * (Dha[e] + Dhb[e] + bhn));
    return (1.0f - z) * n + z * hprev;
  };

  // ---- init: publish s_0 for both layers (tag 1, parity 0); fire-and-forget ----
  pubH(h0reg, stateH(0, 0), 1u);
  pubH(h1reg, stateH(1, 0), 1u);

  // ---- prologue: layer-0 x-part for t=0 ----
  f32x4 acc0  = {0.f, 0.f, 0.f, 0.f};
  f32x4 acc1  = {0.f, 0.f, 0.f, 0.f};
  f32x4 acc1n = {0.f, 0.f, 0.f, 0.f};
  stage_x(dir ? (T_LEN - 1) : 0, OFF_XY);
  __syncthreads();   // also covers Whh LDS staging
  xpart(wf0, OFF_XY, acc0);

  for (int t = 0; t < T_LEN + 2; ++t) {
    const int u = t - 2;
    const bool actH0 = (t < T_LEN);
    const bool actH1 = (u >= 0);
    const bool actY  = (t >= 1 && t <= T_LEN);

    // ---- burst: issue ALL cross-block gathers for this iter, wait ONCE ----
    i32x4 UA[6], UB[6], UC[6];
    if (actH0) issue6(stateH(0, t & 1), UA);
    if (actH1) issue6(stateH(1, t & 1), UB);    // u&1 == t&1
    if (actY)  issue6(stateY((t - 1) & 3), UC);
    asm volatile("s_waitcnt vmcnt(0)" ::: "memory");
    __builtin_amdgcn_sched_barrier(0);
    __syncthreads();   // previous-iter LDS readers done before repack overwrites
    if (actH0) { if (!check6(UA, (unsigned)(t + 1))) retry6(stateH(0, t & 1), (unsigned)(t + 1), UA); repack6(UA, OFF_H0); }
    if (actH1) { if (!check6(UB, (unsigned)(t - 1))) retry6(stateH(1, t & 1), (unsigned)(t - 1), UB); repack6(UB, OFF_H1); }
    if (actY)  { if (!check6(UC, (unsigned)t))       retry6(stateY((t - 1) & 3), (unsigned)t, UC);    repack6(UC, OFF_XY); }
    __syncthreads();

    // ======== Phase A: layer-0 step t ========
    if (actH0) {
      f32x4 ah = {0.f, 0.f, 0.f, 0.f};
      hpart(OFF_WHH0, OFF_H0, acc0, ah);
      dwrite(acc0, ah);
      __syncthreads();
      const float h0new = gates(b_r0, b_z0, b_xn0, b_hn0, h0reg);
      h0reg = h0new;
      pubDual(h0new, stateH(0, (t + 1) & 1), (unsigned)(t + 2),
              stateY(t & 3), (unsigned)(t + 1));
      if (t == T_LEN - 1)
        dout[(size_t)B_SZ * T_LEN * 2 * H_DIM + (size_t)bglobal * 2 * H_DIM + dircol + hcol] = h0new;
    }
    __syncthreads();   // gates0's D reads complete before C's dwrite

    // ======== Phase C2: layer-1 x-part for step t-1 from y tile ========
    if (actY) {
      acc1n[0] = 0.f; acc1n[1] = 0.f; acc1n[2] = 0.f; acc1n[3] = 0.f;
      xpart(wf1, OFF_XY, acc1n);
    }
    __syncthreads();   // C2's XY readers done before B's stage overwrite

    // ======== Phase B: layer-0 x-part for t+1 ========
    if (t + 1 < T_LEN) {
      stage_x(dir ? (T_LEN - 2 - t) : (t + 1), OFF_XY);
      __syncthreads();
      acc0[0] = 0.f; acc0[1] = 0.f; acc0[2] = 0.f; acc0[3] = 0.f;
      xpart(wf0, OFF_XY, acc0);
    }

    // ======== Phase C: layer-1 step u = t-2 ========
    if (actH1) {
      f32x4 ah = {0.f, 0.f, 0.f, 0.f};
      hpart(OFF_WHH1, OFF_H1, acc1, ah);
      dwrite(acc1, ah);
      __syncthreads();
      const float h1new = gates(b_r1, b_z1, b_xn1, b_hn1, h1reg);
      h1reg = h1new;
      pubH(h1new, stateH(1, (u + 1) & 1), (unsigned)(u + 2));
      const int pu = dir ? (T_LEN - 1 - u) : u;
      dout[(size_t)bglobal * T_LEN * 2 * H_DIM + (size_t)pu * 2 * H_DIM + dircol + hcol] = h1new;
      if (u == T_LEN - 1)
        dout[(size_t)B_SZ * T_LEN * 2 * H_DIM +
             (size_t)(B_SZ + bglobal) * 2 * H_DIM + dircol + hcol] = h1new;
    }

    if (actY) acc1 = acc1n;   // step t-1's x-part becomes next C's input
    __syncthreads();          // close iter (covers skipped-phase edge cases)
  }
}

extern "C" void kernel_launch(void* const* d_in, const int* in_sizes, int n_in,
                              void* d_out, int out_size, void* d_ws, size_t ws_size,
                              hipStream_t stream) {
  (void)in_sizes; (void)n_in; (void)out_size; (void)ws_size;
  const float* x    = (const float*)d_in[0];
  const float* enc  = (const float*)d_in[1];
  const float* WihF = (const float*)d_in[2];
  const float* WhhF = (const float*)d_in[3];
  const float* bihF = (const float*)d_in[4];
  const float* bhhF = (const float*)d_in[5];
  const float* WihB = (const float*)d_in[6];
  const float* WhhB = (const float*)d_in[7];
  const float* bihB = (const float*)d_in[8];
  const float* bhhB = (const float*)d_in[9];
  float* out = (float*)d_out;

  char* hT = (char*)d_ws;                 // 768KB tagged h exchange
  char* yT = (char*)d_ws + HT_BYTES;      // 768KB tagged y0 ring
  // zero ALL tags each replay (tags count up from 1; memset-0 never matches)
  hipMemsetAsync(d_ws, 0, HT_BYTES + YT_BYTES, stream);

  dim3 grid(GROUP * 8), block(256);
  gru_fused<<<grid, block, 0, stream>>>(x, enc, WihF, WhhF, bihF, bhhF,
                                        WihB, WhhB, bihB, bhhB, out, hT, yT);
}